// Round 1
// baseline (853.140 us; speedup 1.0000x reference)
//
#include <hip/hip_runtime.h>
#include <cstdint>
#include <cstddef>
#include <math.h>

// RESK GCN forward: 4 graph-conv layers + residuals + log_softmax.
// Strategy: per call, build CSR (grouped by tgt) so aggregation is a
// wave-per-node coalesced gather (no fp32 atomics). GEMMs are thread-per-node
// with wave-uniform weight reads (compiler emits s_loads -> v_fmac v,s,v).

constexpr int SCAN_B = 256;

__global__ void zero_ints(int* __restrict__ p, int n) {
    int i = blockIdx.x * blockDim.x + threadIdx.x;
    if (i < n) p[i] = 0;
}

__global__ void hist_kernel(const int* __restrict__ tgt, int* __restrict__ counts, int E) {
    int e = blockIdx.x * blockDim.x + threadIdx.x;
    if (e < E) atomicAdd(&counts[tgt[e]], 1);
}

// Inclusive block scan of counts; per-block inclusive values + block totals.
__global__ void scan1_kernel(const int* __restrict__ counts, int* __restrict__ tmp_incl,
                             int* __restrict__ blocksums, int n) {
    __shared__ int sd[SCAN_B];
    int i = blockIdx.x * SCAN_B + threadIdx.x;
    int v = (i < n) ? counts[i] : 0;
    sd[threadIdx.x] = v;
    __syncthreads();
    for (int off = 1; off < SCAN_B; off <<= 1) {
        int t = (threadIdx.x >= (unsigned)off) ? sd[threadIdx.x - off] : 0;
        __syncthreads();
        sd[threadIdx.x] += t;
        __syncthreads();
    }
    if (i < n) tmp_incl[i] = sd[threadIdx.x];
    if (threadIdx.x == SCAN_B - 1) blocksums[blockIdx.x] = sd[SCAN_B - 1];
}

// Exclusive scan of block sums (nb <= 512).
__global__ void scan2_kernel(const int* __restrict__ blocksums, int* __restrict__ blockoffs, int nb) {
    __shared__ int sd[512];
    int tid = threadIdx.x;
    int v = (tid < nb) ? blocksums[tid] : 0;
    sd[tid] = v;
    __syncthreads();
    for (int off = 1; off < 512; off <<= 1) {
        int t = (tid >= off) ? sd[tid - off] : 0;
        __syncthreads();
        sd[tid] += t;
        __syncthreads();
    }
    if (tid < nb) blockoffs[tid] = sd[tid] - v;
}

// row_start (exclusive scan) + cursor copy + sentinel row_start[n].
__global__ void scan3_kernel(const int* __restrict__ counts, const int* __restrict__ tmp_incl,
                             const int* __restrict__ blockoffs, int* __restrict__ row_start,
                             int* __restrict__ cursor, int n) {
    int i = blockIdx.x * SCAN_B + threadIdx.x;
    if (i < n) {
        int c = counts[i];
        int excl = tmp_incl[i] - c + blockoffs[blockIdx.x];
        row_start[i] = excl;
        cursor[i] = excl;
        if (i == n - 1) row_start[n] = excl + c;
    }
}

__global__ void fill_kernel(const int* __restrict__ src, const int* __restrict__ tgt,
                            const float* __restrict__ w, int* __restrict__ cursor,
                            int* __restrict__ csr_src, float* __restrict__ csr_w, int E) {
    int e = blockIdx.x * blockDim.x + threadIdx.x;
    if (e < E) {
        int r = tgt[e];
        int pos = atomicAdd(&cursor[r], 1);
        csr_src[pos] = src[e];
        csr_w[pos] = w[e];
    }
}

// support = H @ W. Thread-per-node; W indices are wave-uniform -> scalar loads.
template <int K, int C>
__global__ __launch_bounds__(256) void gemm_kernel(const float* __restrict__ H,
                                                   const float* __restrict__ W,
                                                   float* __restrict__ out, int n) {
    int node = blockIdx.x * blockDim.x + threadIdx.x;
    if (node >= n) return;
    float acc[C];
#pragma unroll
    for (int c = 0; c < C; ++c) acc[c] = 0.f;
    const float4* row = (const float4*)(H + (size_t)node * K);
    for (int k4 = 0; k4 < K / 4; ++k4) {
        float4 xv = row[k4];
        const float* wr = W + (size_t)k4 * 4 * C;
#pragma unroll
        for (int c = 0; c < C; ++c) {
            acc[c] = fmaf(xv.x, wr[c], acc[c]);
            acc[c] = fmaf(xv.y, wr[C + c], acc[c]);
            acc[c] = fmaf(xv.z, wr[2 * C + c], acc[c]);
            acc[c] = fmaf(xv.w, wr[3 * C + c], acc[c]);
        }
    }
    float* orow = out + (size_t)node * C;
#pragma unroll
    for (int c = 0; c < C; c += 4) {
        *(float4*)(orow + c) = make_float4(acc[c], acc[c + 1], acc[c + 2], acc[c + 3]);
    }
}

// Wave-per-node aggregation, C=64: lane = column. out may alias resid
// (each thread reads its own element before writing it).
__global__ __launch_bounds__(256) void agg64_kernel(const float* __restrict__ support,
                                                    const int* __restrict__ row_start,
                                                    const int* __restrict__ csr_src,
                                                    const float* __restrict__ csr_w,
                                                    const float* __restrict__ bias,
                                                    const float* __restrict__ resid,
                                                    float* __restrict__ out, int n) {
    constexpr int C = 64;
    int wid = (blockIdx.x * blockDim.x + threadIdx.x) >> 6;
    int lane = threadIdx.x & 63;
    if (wid >= n) return;
    int beg = row_start[wid], end = row_start[wid + 1];
    float acc = 0.f, acc2 = 0.f;
    int e = beg;
    for (; e + 1 < end; e += 2) {
        int s0 = csr_src[e];     float w0 = csr_w[e];
        int s1 = csr_src[e + 1]; float w1 = csr_w[e + 1];
        acc  = fmaf(support[(size_t)s0 * C + lane], w0, acc);
        acc2 = fmaf(support[(size_t)s1 * C + lane], w1, acc2);
    }
    if (e < end) {
        int s0 = csr_src[e]; float w0 = csr_w[e];
        acc = fmaf(support[(size_t)s0 * C + lane], w0, acc);
    }
    acc += acc2;
    float h = fmaxf(acc + bias[lane], 0.f);
    if (resid) h += resid[(size_t)wid * C + lane];
    out[(size_t)wid * C + lane] = h;
}

// Final layer: C=40 aggregation + bias + fused log_softmax across the wave.
__global__ __launch_bounds__(256) void agg_final_kernel(const float* __restrict__ support,
                                                        const int* __restrict__ row_start,
                                                        const int* __restrict__ csr_src,
                                                        const float* __restrict__ csr_w,
                                                        const float* __restrict__ bias,
                                                        float* __restrict__ out, int n) {
    constexpr int C = 40;
    int wid = (blockIdx.x * blockDim.x + threadIdx.x) >> 6;
    int lane = threadIdx.x & 63;
    if (wid >= n) return;
    bool act = lane < C;
    int beg = row_start[wid], end = row_start[wid + 1];
    float acc = 0.f, acc2 = 0.f;
    int e = beg;
    for (; e + 1 < end; e += 2) {
        int s0 = csr_src[e];     float w0 = csr_w[e];
        int s1 = csr_src[e + 1]; float w1 = csr_w[e + 1];
        if (act) {
            acc  = fmaf(support[(size_t)s0 * C + lane], w0, acc);
            acc2 = fmaf(support[(size_t)s1 * C + lane], w1, acc2);
        }
    }
    if (e < end && act) {
        int s0 = csr_src[e]; float w0 = csr_w[e];
        acc = fmaf(support[(size_t)s0 * C + lane], w0, acc);
    }
    acc += acc2;
    float v = act ? (acc + bias[lane]) : -INFINITY;
    float m = v;
    for (int d = 32; d; d >>= 1) m = fmaxf(m, __shfl_xor(m, d));
    float ex = act ? expf(v - m) : 0.f;
    for (int d = 32; d; d >>= 1) ex += __shfl_xor(ex, d);
    float lse = m + logf(ex);
    if (act) out[(size_t)wid * C + lane] = v - lse;
}

extern "C" void kernel_launch(void* const* d_in, const int* in_sizes, int n_in,
                              void* d_out, int out_size, void* d_ws, size_t ws_size,
                              hipStream_t stream) {
    const float* x   = (const float*)d_in[0];
    const int*   src = (const int*)d_in[1];
    const int*   tgt = (const int*)d_in[2];
    const float* mw  = (const float*)d_in[3];
    const float* W0  = (const float*)d_in[4];
    const float* b0  = (const float*)d_in[5];
    const float* W1  = (const float*)d_in[6];
    const float* b1  = (const float*)d_in[7];
    const float* W2  = (const float*)d_in[8];
    const float* b2  = (const float*)d_in[9];
    const float* W3  = (const float*)d_in[10];
    const float* b3  = (const float*)d_in[11];
    float* out = (float*)d_out;

    const int N = in_sizes[0] / 128;
    const int E = in_sizes[1];
    const int NBLK = (N + SCAN_B - 1) / SCAN_B;  // 391 for N=100000 (<=512 req'd by scan2)

    // Workspace carve-out (~66 MB total)
    char* p = (char*)d_ws;
    auto carve = [&](size_t bytes) {
        char* r = p;
        p += (bytes + 255) & ~size_t(255);
        return r;
    };
    int*   counts    = (int*)carve((size_t)N * 4);
    int*   row_start = (int*)carve((size_t)(N + 1) * 4);
    int*   cursor    = (int*)carve((size_t)N * 4);
    int*   tmp_incl  = (int*)carve((size_t)N * 4);
    int*   blocksums = (int*)carve((size_t)NBLK * 4);
    int*   blockoffs = (int*)carve((size_t)NBLK * 4);
    int*   csr_src   = (int*)carve((size_t)E * 4);
    float* csr_w     = (float*)carve((size_t)E * 4);
    float* support   = (float*)carve((size_t)N * 64 * 4);
    float* h         = (float*)carve((size_t)N * 64 * 4);

    int nthreads = 256;
    int nblocksN = (N + nthreads - 1) / nthreads;
    int nblocksE = (E + nthreads - 1) / nthreads;
    int ablocks  = (N + 3) / 4;  // 4 waves/block, wave per node

    // ---- CSR build (per call; ws is re-poisoned between calls) ----
    zero_ints<<<nblocksN, nthreads, 0, stream>>>(counts, N);
    hist_kernel<<<nblocksE, nthreads, 0, stream>>>(tgt, counts, E);
    scan1_kernel<<<NBLK, SCAN_B, 0, stream>>>(counts, tmp_incl, blocksums, N);
    scan2_kernel<<<1, 512, 0, stream>>>(blocksums, blockoffs, NBLK);
    scan3_kernel<<<NBLK, SCAN_B, 0, stream>>>(counts, tmp_incl, blockoffs, row_start, cursor, N);
    fill_kernel<<<nblocksE, nthreads, 0, stream>>>(src, tgt, mw, cursor, csr_src, csr_w, E);

    // ---- Layer 0: h = relu(A @ (x @ W0) + b0) ----
    gemm_kernel<128, 64><<<nblocksN, nthreads, 0, stream>>>(x, W0, support, N);
    agg64_kernel<<<ablocks, nthreads, 0, stream>>>(support, row_start, csr_src, csr_w, b0,
                                                   nullptr, h, N);
    // ---- Layer 1: h = relu(A @ (h @ W1) + b1) + h (in-place residual) ----
    gemm_kernel<64, 64><<<nblocksN, nthreads, 0, stream>>>(h, W1, support, N);
    agg64_kernel<<<ablocks, nthreads, 0, stream>>>(support, row_start, csr_src, csr_w, b1,
                                                   h, h, N);
    // ---- Layer 2 ----
    gemm_kernel<64, 64><<<nblocksN, nthreads, 0, stream>>>(h, W2, support, N);
    agg64_kernel<<<ablocks, nthreads, 0, stream>>>(support, row_start, csr_src, csr_w, b2,
                                                   h, h, N);
    // ---- Layer 3: out = log_softmax(A @ (h @ W3) + b3) ----
    gemm_kernel<64, 40><<<nblocksN, nthreads, 0, stream>>>(h, W3, support, N);
    agg_final_kernel<<<ablocks, nthreads, 0, stream>>>(support, row_start, csr_src, csr_w, b3,
                                                       out, N);
}

// Round 2
// 687.599 us; speedup vs baseline: 1.2408x; 1.2408x over previous
//
#include <hip/hip_runtime.h>
#include <cstdint>
#include <cstddef>
#include <math.h>

// RESK GCN forward: 4 graph-conv layers + residuals + log_softmax.
// R2: CSR entry packed as int2 {src, w} (one 8B scattered store, halves fill
// write amplification); agg uses readfirstlane-uniform edge ranges (scalar
// descriptor loads) + 4 independent gather chains for latency hiding.

constexpr int SCAN_B = 256;

__global__ void zero_ints(int* __restrict__ p, int n) {
    int i = blockIdx.x * blockDim.x + threadIdx.x;
    if (i < n) p[i] = 0;
}

__global__ void hist_kernel(const int* __restrict__ tgt, int* __restrict__ counts, int E) {
    int e = blockIdx.x * blockDim.x + threadIdx.x;
    if (e < E) atomicAdd(&counts[tgt[e]], 1);
}

// Inclusive block scan of counts; per-block inclusive values + block totals.
__global__ void scan1_kernel(const int* __restrict__ counts, int* __restrict__ tmp_incl,
                             int* __restrict__ blocksums, int n) {
    __shared__ int sd[SCAN_B];
    int i = blockIdx.x * SCAN_B + threadIdx.x;
    int v = (i < n) ? counts[i] : 0;
    sd[threadIdx.x] = v;
    __syncthreads();
    for (int off = 1; off < SCAN_B; off <<= 1) {
        int t = (threadIdx.x >= (unsigned)off) ? sd[threadIdx.x - off] : 0;
        __syncthreads();
        sd[threadIdx.x] += t;
        __syncthreads();
    }
    if (i < n) tmp_incl[i] = sd[threadIdx.x];
    if (threadIdx.x == SCAN_B - 1) blocksums[blockIdx.x] = sd[SCAN_B - 1];
}

// Exclusive scan of block sums (nb <= 512).
__global__ void scan2_kernel(const int* __restrict__ blocksums, int* __restrict__ blockoffs, int nb) {
    __shared__ int sd[512];
    int tid = threadIdx.x;
    int v = (tid < nb) ? blocksums[tid] : 0;
    sd[tid] = v;
    __syncthreads();
    for (int off = 1; off < 512; off <<= 1) {
        int t = (tid >= off) ? sd[tid - off] : 0;
        __syncthreads();
        sd[tid] += t;
        __syncthreads();
    }
    if (tid < nb) blockoffs[tid] = sd[tid] - v;
}

// row_start (exclusive scan) + cursor copy + sentinel row_start[n].
__global__ void scan3_kernel(const int* __restrict__ counts, const int* __restrict__ tmp_incl,
                             const int* __restrict__ blockoffs, int* __restrict__ row_start,
                             int* __restrict__ cursor, int n) {
    int i = blockIdx.x * SCAN_B + threadIdx.x;
    if (i < n) {
        int c = counts[i];
        int excl = tmp_incl[i] - c + blockoffs[blockIdx.x];
        row_start[i] = excl;
        cursor[i] = excl;
        if (i == n - 1) row_start[n] = excl + c;
    }
}

__global__ void fill_kernel(const int* __restrict__ src, const int* __restrict__ tgt,
                            const float* __restrict__ w, int* __restrict__ cursor,
                            int2* __restrict__ csr, int E) {
    int e = blockIdx.x * blockDim.x + threadIdx.x;
    if (e < E) {
        int r = tgt[e];
        int pos = atomicAdd(&cursor[r], 1);
        csr[pos] = make_int2(src[e], __float_as_int(w[e]));
    }
}

// support = H @ W. Thread-per-node; W indices are wave-uniform -> scalar loads.
template <int K, int C>
__global__ __launch_bounds__(256) void gemm_kernel(const float* __restrict__ H,
                                                   const float* __restrict__ W,
                                                   float* __restrict__ out, int n) {
    int node = blockIdx.x * blockDim.x + threadIdx.x;
    if (node >= n) return;
    float acc[C];
#pragma unroll
    for (int c = 0; c < C; ++c) acc[c] = 0.f;
    const float4* row = (const float4*)(H + (size_t)node * K);
    for (int k4 = 0; k4 < K / 4; ++k4) {
        float4 xv = row[k4];
        const float* wr = W + (size_t)k4 * 4 * C;
#pragma unroll
        for (int c = 0; c < C; ++c) {
            acc[c] = fmaf(xv.x, wr[c], acc[c]);
            acc[c] = fmaf(xv.y, wr[C + c], acc[c]);
            acc[c] = fmaf(xv.z, wr[2 * C + c], acc[c]);
            acc[c] = fmaf(xv.w, wr[3 * C + c], acc[c]);
        }
    }
    float* orow = out + (size_t)node * C;
#pragma unroll
    for (int c = 0; c < C; c += 4) {
        *(float4*)(orow + c) = make_float4(acc[c], acc[c + 1], acc[c + 2], acc[c + 3]);
    }
}

// Wave-per-node aggregation, C=64: lane = column. Edge range made
// wave-uniform via readfirstlane so descriptor loads go scalar; 4
// independent gather chains hide L3 latency. out may alias resid.
__global__ __launch_bounds__(256) void agg64_kernel(const float* __restrict__ support,
                                                    const int* __restrict__ row_start,
                                                    const int2* __restrict__ csr,
                                                    const float* __restrict__ bias,
                                                    const float* __restrict__ resid,
                                                    float* __restrict__ out, int n) {
    constexpr int C = 64;
    int wid = (blockIdx.x * blockDim.x + threadIdx.x) >> 6;
    int lane = threadIdx.x & 63;
    if (wid >= n) return;
    int beg = __builtin_amdgcn_readfirstlane(row_start[wid]);
    int end = __builtin_amdgcn_readfirstlane(row_start[wid + 1]);
    float a0 = 0.f, a1 = 0.f, a2 = 0.f, a3 = 0.f;
    int e = beg;
    for (; e + 3 < end; e += 4) {
        int2 d0 = csr[e], d1 = csr[e + 1], d2 = csr[e + 2], d3 = csr[e + 3];
        a0 = fmaf(support[(size_t)d0.x * C + lane], __int_as_float(d0.y), a0);
        a1 = fmaf(support[(size_t)d1.x * C + lane], __int_as_float(d1.y), a1);
        a2 = fmaf(support[(size_t)d2.x * C + lane], __int_as_float(d2.y), a2);
        a3 = fmaf(support[(size_t)d3.x * C + lane], __int_as_float(d3.y), a3);
    }
    for (; e < end; ++e) {
        int2 d0 = csr[e];
        a0 = fmaf(support[(size_t)d0.x * C + lane], __int_as_float(d0.y), a0);
    }
    float acc = (a0 + a1) + (a2 + a3);
    float h = fmaxf(acc + bias[lane], 0.f);
    if (resid) h += resid[(size_t)wid * C + lane];
    out[(size_t)wid * C + lane] = h;
}

// Final layer: C=40 aggregation + bias + fused log_softmax across the wave.
__global__ __launch_bounds__(256) void agg_final_kernel(const float* __restrict__ support,
                                                        const int* __restrict__ row_start,
                                                        const int2* __restrict__ csr,
                                                        const float* __restrict__ bias,
                                                        float* __restrict__ out, int n) {
    constexpr int C = 40;
    int wid = (blockIdx.x * blockDim.x + threadIdx.x) >> 6;
    int lane = threadIdx.x & 63;
    if (wid >= n) return;
    bool act = lane < C;
    int beg = __builtin_amdgcn_readfirstlane(row_start[wid]);
    int end = __builtin_amdgcn_readfirstlane(row_start[wid + 1]);
    float a0 = 0.f, a1 = 0.f, a2 = 0.f, a3 = 0.f;
    int col = act ? lane : 0;  // keep all lanes' loads in-bounds, mask at the end
    int e = beg;
    for (; e + 3 < end; e += 4) {
        int2 d0 = csr[e], d1 = csr[e + 1], d2 = csr[e + 2], d3 = csr[e + 3];
        a0 = fmaf(support[(size_t)d0.x * C + col], __int_as_float(d0.y), a0);
        a1 = fmaf(support[(size_t)d1.x * C + col], __int_as_float(d1.y), a1);
        a2 = fmaf(support[(size_t)d2.x * C + col], __int_as_float(d2.y), a2);
        a3 = fmaf(support[(size_t)d3.x * C + col], __int_as_float(d3.y), a3);
    }
    for (; e < end; ++e) {
        int2 d0 = csr[e];
        a0 = fmaf(support[(size_t)d0.x * C + col], __int_as_float(d0.y), a0);
    }
    float acc = (a0 + a1) + (a2 + a3);
    float v = act ? (acc + bias[lane]) : -INFINITY;
    float m = v;
    for (int d = 32; d; d >>= 1) m = fmaxf(m, __shfl_xor(m, d));
    float ex = act ? expf(v - m) : 0.f;
    for (int d = 32; d; d >>= 1) ex += __shfl_xor(ex, d);
    float lse = m + logf(ex);
    if (act) out[(size_t)wid * C + lane] = v - lse;
}

extern "C" void kernel_launch(void* const* d_in, const int* in_sizes, int n_in,
                              void* d_out, int out_size, void* d_ws, size_t ws_size,
                              hipStream_t stream) {
    const float* x   = (const float*)d_in[0];
    const int*   src = (const int*)d_in[1];
    const int*   tgt = (const int*)d_in[2];
    const float* mw  = (const float*)d_in[3];
    const float* W0  = (const float*)d_in[4];
    const float* b0  = (const float*)d_in[5];
    const float* W1  = (const float*)d_in[6];
    const float* b1  = (const float*)d_in[7];
    const float* W2  = (const float*)d_in[8];
    const float* b2  = (const float*)d_in[9];
    const float* W3  = (const float*)d_in[10];
    const float* b3  = (const float*)d_in[11];
    float* out = (float*)d_out;

    const int N = in_sizes[0] / 128;
    const int E = in_sizes[1];
    const int NBLK = (N + SCAN_B - 1) / SCAN_B;  // 391 for N=100000 (<=512 req'd by scan2)

    // Workspace carve-out (~66 MB total)
    char* p = (char*)d_ws;
    auto carve = [&](size_t bytes) {
        char* r = p;
        p += (bytes + 255) & ~size_t(255);
        return r;
    };
    int*   counts    = (int*)carve((size_t)N * 4);
    int*   row_start = (int*)carve((size_t)(N + 1) * 4);
    int*   cursor    = (int*)carve((size_t)N * 4);
    int*   tmp_incl  = (int*)carve((size_t)N * 4);
    int*   blocksums = (int*)carve((size_t)NBLK * 4);
    int*   blockoffs = (int*)carve((size_t)NBLK * 4);
    int2*  csr       = (int2*)carve((size_t)E * 8);
    float* support   = (float*)carve((size_t)N * 64 * 4);
    float* h         = (float*)carve((size_t)N * 64 * 4);

    int nthreads = 256;
    int nblocksN = (N + nthreads - 1) / nthreads;
    int nblocksE = (E + nthreads - 1) / nthreads;
    int ablocks  = (N + 3) / 4;  // 4 waves/block, wave per node

    // ---- CSR build (per call; ws is re-poisoned between calls) ----
    zero_ints<<<nblocksN, nthreads, 0, stream>>>(counts, N);
    hist_kernel<<<nblocksE, nthreads, 0, stream>>>(tgt, counts, E);
    scan1_kernel<<<NBLK, SCAN_B, 0, stream>>>(counts, tmp_incl, blocksums, N);
    scan2_kernel<<<1, 512, 0, stream>>>(blocksums, blockoffs, NBLK);
    scan3_kernel<<<NBLK, SCAN_B, 0, stream>>>(counts, tmp_incl, blockoffs, row_start, cursor, N);
    fill_kernel<<<nblocksE, nthreads, 0, stream>>>(src, tgt, mw, cursor, csr, E);

    // ---- Layer 0: h = relu(A @ (x @ W0) + b0) ----
    gemm_kernel<128, 64><<<nblocksN, nthreads, 0, stream>>>(x, W0, support, N);
    agg64_kernel<<<ablocks, nthreads, 0, stream>>>(support, row_start, csr, b0, nullptr, h, N);
    // ---- Layer 1: h = relu(A @ (h @ W1) + b1) + h (in-place residual) ----
    gemm_kernel<64, 64><<<nblocksN, nthreads, 0, stream>>>(h, W1, support, N);
    agg64_kernel<<<ablocks, nthreads, 0, stream>>>(support, row_start, csr, b1, h, h, N);
    // ---- Layer 2 ----
    gemm_kernel<64, 64><<<nblocksN, nthreads, 0, stream>>>(h, W2, support, N);
    agg64_kernel<<<ablocks, nthreads, 0, stream>>>(support, row_start, csr, b2, h, h, N);
    // ---- Layer 3: out = log_softmax(A @ (h @ W3) + b3) ----
    gemm_kernel<64, 40><<<nblocksN, nthreads, 0, stream>>>(h, W3, support, N);
    agg_final_kernel<<<ablocks, nthreads, 0, stream>>>(support, row_start, csr, b3, out, N);
}

// Round 3
// 655.052 us; speedup vs baseline: 1.3024x; 1.0497x over previous
//
#include <hip/hip_runtime.h>
#include <cstdint>
#include <cstddef>
#include <math.h>

// RESK GCN forward: 4 graph-conv layers + residuals + log_softmax.
// R3: CSR build via two-level XCD-aware counting sort.
//   pass1: append edges to (tgt>>8, blockIdx&7) streams -> sequential 8B
//          stores per stream, single-XCD ownership, ~1x write amplification
//          (old fill_kernel: 64B line written per 8B store, 100 MB traffic).
//   bscan: 512-wide scan of bucket totals -> bucket base offsets.
//   pass2: block-per-bucket; stage edges in LDS, 256-row LDS histogram+scan
//          (produces row_start directly -> hist/scan kernels deleted),
//          scatter into 32 KB CSR window (single-L2 locality).
// Agg: wave-per-node gather, 8 independent chains.

constexpr int XC = 8;           // XCD copies per bucket
constexpr int CAP = 768;        // entries per (bucket, copy); mean 512, +11 sigma
constexpr int LCAP = 5120;      // LDS staging entries per bucket; mean 4096, +16 sigma

__global__ void zero_ints(int* __restrict__ p, int n) {
    int i = blockIdx.x * blockDim.x + threadIdx.x;
    if (i < n) p[i] = 0;
}

// Entry packing: x = src | (local_tgt << 20)  (src < 2^17, local_tgt < 256)
__global__ void pass1_kernel(const int* __restrict__ src, const int* __restrict__ tgt,
                             const float* __restrict__ w, int* __restrict__ bcur,
                             int2* __restrict__ bkt, int E) {
    int e = blockIdx.x * blockDim.x + threadIdx.x;
    if (e >= E) return;
    int x = blockIdx.x & (XC - 1);
    int r = tgt[e];
    int b = r >> 8;
    int lt = r & 255;
    int pos = atomicAdd(&bcur[b * XC + x], 1);
    if (pos < CAP)
        bkt[(size_t)(b * XC + x) * CAP + pos] = make_int2(src[e] | (lt << 20),
                                                          __float_as_int(w[e]));
}

// Exclusive scan over bucket totals (NB <= 512). Also writes row_start[N]=E.
__global__ void bscan_kernel(const int* __restrict__ bcur, int* __restrict__ bbase,
                             int* __restrict__ row_start, int NB, int N, int E) {
    __shared__ int sd[512];
    int tid = threadIdx.x;
    int tot = 0;
    if (tid < NB)
        for (int x = 0; x < XC; ++x) tot += bcur[tid * XC + x];
    sd[tid] = tot;
    __syncthreads();
    for (int off = 1; off < 512; off <<= 1) {
        int t = (tid >= off) ? sd[tid - off] : 0;
        __syncthreads();
        sd[tid] += t;
        __syncthreads();
    }
    if (tid < NB) bbase[tid] = sd[tid] - tot;
    if (tid == 0) row_start[N] = E;
}

// Block-per-bucket: stage in LDS, histogram rows, scan -> row_start, scatter.
__global__ __launch_bounds__(256) void pass2_kernel(const int2* __restrict__ bkt,
                                                    const int* __restrict__ bcur,
                                                    const int* __restrict__ bbase,
                                                    int2* __restrict__ csr,
                                                    int* __restrict__ row_start, int N) {
    __shared__ int2 stage[LCAP];
    __shared__ int hist[256];
    __shared__ int offs[256];
    __shared__ int segoff[XC + 1];
    int b = blockIdx.x;
    int tid = threadIdx.x;
    hist[tid] = 0;
    if (tid == 0) {
        int s = 0;
        for (int x = 0; x < XC; ++x) { segoff[x] = s; s += bcur[b * XC + x]; }
        segoff[XC] = s;
    }
    __syncthreads();
    // phase A: read segments, histogram local rows, stage in LDS
    for (int x = 0; x < XC; ++x) {
        int base = segoff[x];
        int cnt = segoff[x + 1] - base;
        const int2* seg = bkt + (size_t)(b * XC + x) * CAP;
        for (int i = tid; i < cnt; i += 256) {
            int2 en = seg[i];
            atomicAdd(&hist[en.x >> 20], 1);
            int li = base + i;
            if (li < LCAP) stage[li] = en;
        }
    }
    __syncthreads();
    // scan hist -> exclusive offsets; emit row_start
    int v = hist[tid];
    offs[tid] = v;
    __syncthreads();
    for (int off = 1; off < 256; off <<= 1) {
        int t = (tid >= off) ? offs[tid - off] : 0;
        __syncthreads();
        offs[tid] += t;
        __syncthreads();
    }
    int excl = offs[tid] - v;
    int gbase = bbase[b];
    int row = (b << 8) + tid;
    if (row < N) row_start[row] = gbase + excl;
    __syncthreads();
    hist[tid] = excl;  // reuse as row cursor
    __syncthreads();
    // phase B: scatter into bucket's CSR window
    int total = segoff[XC];
    for (int i = tid; i < total; i += 256) {
        int2 en;
        if (i < LCAP) en = stage[i];
        else {
            int x = XC - 1;
            while (x > 0 && segoff[x] > i) --x;
            en = bkt[(size_t)(b * XC + x) * CAP + (i - segoff[x])];
        }
        int lt = en.x >> 20;
        int pos = atomicAdd(&hist[lt], 1);
        csr[gbase + pos] = make_int2(en.x & 0x1FFFF, en.y);
    }
}

// support = H @ W. Thread-per-node; W indices are wave-uniform -> scalar loads.
template <int K, int C>
__global__ __launch_bounds__(256) void gemm_kernel(const float* __restrict__ H,
                                                   const float* __restrict__ W,
                                                   float* __restrict__ out, int n) {
    int node = blockIdx.x * blockDim.x + threadIdx.x;
    if (node >= n) return;
    float acc[C];
#pragma unroll
    for (int c = 0; c < C; ++c) acc[c] = 0.f;
    const float4* row = (const float4*)(H + (size_t)node * K);
    for (int k4 = 0; k4 < K / 4; ++k4) {
        float4 xv = row[k4];
        const float* wr = W + (size_t)k4 * 4 * C;
#pragma unroll
        for (int c = 0; c < C; ++c) {
            acc[c] = fmaf(xv.x, wr[c], acc[c]);
            acc[c] = fmaf(xv.y, wr[C + c], acc[c]);
            acc[c] = fmaf(xv.z, wr[2 * C + c], acc[c]);
            acc[c] = fmaf(xv.w, wr[3 * C + c], acc[c]);
        }
    }
    float* orow = out + (size_t)node * C;
#pragma unroll
    for (int c = 0; c < C; c += 4) {
        *(float4*)(orow + c) = make_float4(acc[c], acc[c + 1], acc[c + 2], acc[c + 3]);
    }
}

// Wave-per-node aggregation, C=64: lane = column; 8 independent gather
// chains hide L2/L3 latency. out may alias resid (per-thread own element).
__global__ __launch_bounds__(256) void agg64_kernel(const float* __restrict__ support,
                                                    const int* __restrict__ row_start,
                                                    const int2* __restrict__ csr,
                                                    const float* __restrict__ bias,
                                                    const float* __restrict__ resid,
                                                    float* __restrict__ out, int n) {
    constexpr int C = 64;
    int wid = (blockIdx.x * blockDim.x + threadIdx.x) >> 6;
    int lane = threadIdx.x & 63;
    if (wid >= n) return;
    float bv = bias[lane];
    int beg = __builtin_amdgcn_readfirstlane(row_start[wid]);
    int end = __builtin_amdgcn_readfirstlane(row_start[wid + 1]);
    float a0 = 0.f, a1 = 0.f, a2 = 0.f, a3 = 0.f;
    float a4 = 0.f, a5 = 0.f, a6 = 0.f, a7 = 0.f;
    int e = beg;
    for (; e + 7 < end; e += 8) {
        int2 d0 = csr[e],     d1 = csr[e + 1], d2 = csr[e + 2], d3 = csr[e + 3];
        int2 d4 = csr[e + 4], d5 = csr[e + 5], d6 = csr[e + 6], d7 = csr[e + 7];
        a0 = fmaf(support[(size_t)d0.x * C + lane], __int_as_float(d0.y), a0);
        a1 = fmaf(support[(size_t)d1.x * C + lane], __int_as_float(d1.y), a1);
        a2 = fmaf(support[(size_t)d2.x * C + lane], __int_as_float(d2.y), a2);
        a3 = fmaf(support[(size_t)d3.x * C + lane], __int_as_float(d3.y), a3);
        a4 = fmaf(support[(size_t)d4.x * C + lane], __int_as_float(d4.y), a4);
        a5 = fmaf(support[(size_t)d5.x * C + lane], __int_as_float(d5.y), a5);
        a6 = fmaf(support[(size_t)d6.x * C + lane], __int_as_float(d6.y), a6);
        a7 = fmaf(support[(size_t)d7.x * C + lane], __int_as_float(d7.y), a7);
    }
    for (; e + 3 < end; e += 4) {
        int2 d0 = csr[e], d1 = csr[e + 1], d2 = csr[e + 2], d3 = csr[e + 3];
        a0 = fmaf(support[(size_t)d0.x * C + lane], __int_as_float(d0.y), a0);
        a1 = fmaf(support[(size_t)d1.x * C + lane], __int_as_float(d1.y), a1);
        a2 = fmaf(support[(size_t)d2.x * C + lane], __int_as_float(d2.y), a2);
        a3 = fmaf(support[(size_t)d3.x * C + lane], __int_as_float(d3.y), a3);
    }
    for (; e < end; ++e) {
        int2 d0 = csr[e];
        a0 = fmaf(support[(size_t)d0.x * C + lane], __int_as_float(d0.y), a0);
    }
    float acc = ((a0 + a1) + (a2 + a3)) + ((a4 + a5) + (a6 + a7));
    float h = fmaxf(acc + bv, 0.f);
    if (resid) h += resid[(size_t)wid * C + lane];
    out[(size_t)wid * C + lane] = h;
}

// Final layer: C=40 aggregation + bias + fused log_softmax across the wave.
__global__ __launch_bounds__(256) void agg_final_kernel(const float* __restrict__ support,
                                                        const int* __restrict__ row_start,
                                                        const int2* __restrict__ csr,
                                                        const float* __restrict__ bias,
                                                        float* __restrict__ out, int n) {
    constexpr int C = 40;
    int wid = (blockIdx.x * blockDim.x + threadIdx.x) >> 6;
    int lane = threadIdx.x & 63;
    if (wid >= n) return;
    bool act = lane < C;
    int beg = __builtin_amdgcn_readfirstlane(row_start[wid]);
    int end = __builtin_amdgcn_readfirstlane(row_start[wid + 1]);
    float a0 = 0.f, a1 = 0.f, a2 = 0.f, a3 = 0.f;
    int col = act ? lane : 0;  // keep all lanes' loads in-bounds, mask at the end
    int e = beg;
    for (; e + 3 < end; e += 4) {
        int2 d0 = csr[e], d1 = csr[e + 1], d2 = csr[e + 2], d3 = csr[e + 3];
        a0 = fmaf(support[(size_t)d0.x * C + col], __int_as_float(d0.y), a0);
        a1 = fmaf(support[(size_t)d1.x * C + col], __int_as_float(d1.y), a1);
        a2 = fmaf(support[(size_t)d2.x * C + col], __int_as_float(d2.y), a2);
        a3 = fmaf(support[(size_t)d3.x * C + col], __int_as_float(d3.y), a3);
    }
    for (; e < end; ++e) {
        int2 d0 = csr[e];
        a0 = fmaf(support[(size_t)d0.x * C + col], __int_as_float(d0.y), a0);
    }
    float acc = (a0 + a1) + (a2 + a3);
    float v = act ? (acc + bias[lane]) : -INFINITY;
    float m = v;
    for (int d = 32; d; d >>= 1) m = fmaxf(m, __shfl_xor(m, d));
    float ex = act ? expf(v - m) : 0.f;
    for (int d = 32; d; d >>= 1) ex += __shfl_xor(ex, d);
    float lse = m + logf(ex);
    if (act) out[(size_t)wid * C + lane] = v - lse;
}

extern "C" void kernel_launch(void* const* d_in, const int* in_sizes, int n_in,
                              void* d_out, int out_size, void* d_ws, size_t ws_size,
                              hipStream_t stream) {
    const float* x   = (const float*)d_in[0];
    const int*   src = (const int*)d_in[1];
    const int*   tgt = (const int*)d_in[2];
    const float* mw  = (const float*)d_in[3];
    const float* W0  = (const float*)d_in[4];
    const float* b0  = (const float*)d_in[5];
    const float* W1  = (const float*)d_in[6];
    const float* b1  = (const float*)d_in[7];
    const float* W2  = (const float*)d_in[8];
    const float* b2  = (const float*)d_in[9];
    const float* W3  = (const float*)d_in[10];
    const float* b3  = (const float*)d_in[11];
    float* out = (float*)d_out;

    const int N = in_sizes[0] / 128;
    const int E = in_sizes[1];
    const int NB = (N + 255) >> 8;  // 391 target-buckets (<=512 for bscan)

    // Workspace carve-out. bkt overlays support/h (dead after pass2).
    char* p = (char*)d_ws;
    auto carve = [&](size_t bytes) {
        char* r = p;
        p += (bytes + 255) & ~size_t(255);
        return r;
    };
    int2*  csr       = (int2*)carve((size_t)E * 8);
    int*   row_start = (int*)carve((size_t)(N + 1) * 4);
    int*   bcur      = (int*)carve((size_t)NB * XC * 4);
    int*   bbase     = (int*)carve((size_t)NB * 4);
    char*  big       = carve((size_t)N * 64 * 4 * 2);
    float* support   = (float*)big;
    float* h         = (float*)(big + (size_t)N * 64 * 4);
    int2*  bkt       = (int2*)big;  // NB*XC*CAP*8 = 19.2 MB < 25.6 MB support span

    int nthreads = 256;
    int nblocksN = (N + nthreads - 1) / nthreads;
    int nblocksE = (E + nthreads - 1) / nthreads;
    int ablocks  = (N + 3) / 4;  // 4 waves/block, wave per node

    // ---- CSR build ----
    zero_ints<<<(NB * XC + 255) / 256, nthreads, 0, stream>>>(bcur, NB * XC);
    pass1_kernel<<<nblocksE, nthreads, 0, stream>>>(src, tgt, mw, bcur, bkt, E);
    bscan_kernel<<<1, 512, 0, stream>>>(bcur, bbase, row_start, NB, N, E);
    pass2_kernel<<<NB, nthreads, 0, stream>>>(bkt, bcur, bbase, csr, row_start, N);

    // ---- Layer 0: h = relu(A @ (x @ W0) + b0) ----
    gemm_kernel<128, 64><<<nblocksN, nthreads, 0, stream>>>(x, W0, support, N);
    agg64_kernel<<<ablocks, nthreads, 0, stream>>>(support, row_start, csr, b0, nullptr, h, N);
    // ---- Layer 1: h = relu(A @ (h @ W1) + b1) + h (in-place residual) ----
    gemm_kernel<64, 64><<<nblocksN, nthreads, 0, stream>>>(h, W1, support, N);
    agg64_kernel<<<ablocks, nthreads, 0, stream>>>(support, row_start, csr, b1, h, h, N);
    // ---- Layer 2 ----
    gemm_kernel<64, 64><<<nblocksN, nthreads, 0, stream>>>(h, W2, support, N);
    agg64_kernel<<<ablocks, nthreads, 0, stream>>>(support, row_start, csr, b2, h, h, N);
    // ---- Layer 3: out = log_softmax(A @ (h @ W3) + b3) ----
    gemm_kernel<64, 40><<<nblocksN, nthreads, 0, stream>>>(h, W3, support, N);
    agg_final_kernel<<<ablocks, nthreads, 0, stream>>>(support, row_start, csr, b3, out, N);
}